// Round 5
// baseline (431.699 us; speedup 1.0000x reference)
//
#include <hip/hip_runtime.h>
#include <hip/hip_bf16.h>
#include <cstdint>
#include <type_traits>

#define GLOBAL_AS __attribute__((address_space(1)))
#define LDS_AS    __attribute__((address_space(3)))

typedef short bf16x8 __attribute__((ext_vector_type(8)));
typedef short short8_t __attribute__((ext_vector_type(8)));
typedef float f32x4  __attribute__((ext_vector_type(4)));

static constexpr int E_DIM = 1024;   // hidden
static constexpr int HD = 64;
static constexpr int QKV_STRIDE = 3072;
static constexpr int KDIM = 1024;        // K for both GEMMs
static constexpr int NKH  = KDIM / 32;   // 32 k-halves (phases)

__device__ __forceinline__ float b2f(short s) {
    union { unsigned u; float f; } x;
    x.u = ((unsigned)(unsigned short)s) << 16;
    return x.f;
}
__device__ __forceinline__ short f2b(float f) {
    union { float f; unsigned u; } x; x.f = f;
    unsigned r = x.u + 0x7FFF + ((x.u >> 16) & 1);
    return (short)(r >> 16);
}

// ---------------- fp32 -> bf16 convert ----------------
__global__ __launch_bounds__(256) void k_convert(const float* __restrict__ in,
                                                 short* __restrict__ out, int n4) {
    int i = blockIdx.x * 256 + threadIdx.x;
    if (i >= n4) return;
    float4 v = reinterpret_cast<const float4*>(in)[i];
    short4 o;
    o.x = f2b(v.x); o.y = f2b(v.y); o.z = f2b(v.z); o.w = f2b(v.w);
    reinterpret_cast<short4*>(out)[i] = o;
}

// ---------------- bias concat [bq | bk | bv] ----------
__global__ __launch_bounds__(256) void k_bcat(const float* __restrict__ bq,
                                              const float* __restrict__ bk,
                                              const float* __restrict__ bv,
                                              float* __restrict__ o) {
    int i = blockIdx.x * 256 + threadIdx.x;
    float v = (i < 1024) ? bq[i] : (i < 2048 ? bk[i - 1024] : bv[i - 2048]);
    o[i] = v;
}

// ======== 256x256 merged-phase bf16 GEMM (ring-4, uniform vmcnt(8)) ========
// C[M][N] = A[M][K] * B[N][K]^T + bias. K = KDIM = 1024.
// 512 threads = 8 waves (2M x 4N), per-wave 128x64 output.
// LDS: ring of 4 regions per matrix, region = one k-half (256 rows x 32 k).
// Phase h (h = 0..31): read region h%4 (12 ds_read_b128), stage k-half h+3
// into region (h+3)%4, barrier, 32 MFMA, vmcnt(8), barrier.
// FIFO invariant: queue at phase end = 12 loads (phases h-2,h-1,h);
// vmcnt(8) retires phase-(h-2)'s 4 loads = region consumed at phase h+1.
template <typename OutT>
__global__ __launch_bounds__(512, 2) void k_gemm256(
    const short* __restrict__ A,    // [M][KDIM]
    const short* __restrict__ Bm,   // [N][KDIM]
    const float* __restrict__ bias, // [N]
    OutT* __restrict__ C,           // [M][N]
    int NT_N, int N)
{
    __shared__ short lds[4][2][8192];   // [region][A=0/B=1][16 KiB]

    const int tid  = threadIdx.x;
    const int lane = tid & 63;
    const int wv   = tid >> 6;      // 0..7
    const int wr   = wv >> 2;       // 0..1  (M half)
    const int wc   = wv & 3;        // 0..3  (N quarter)
    const int frow = lane & 15;
    const int ks   = lane >> 4;     // k-slot 0..3 within k-half

    // bijective XCD swizzle (grid % 8 == 0), n-fastest so neighbors share A-panel
    const int nwg  = gridDim.x;
    const int nper = nwg >> 3;
    const int bid  = blockIdx.x;
    const int swz  = (bid & 7) * nper + (bid >> 3);
    const int m0   = (swz / NT_N) * 256;
    const int n0   = (swz % NT_N) * 256;

    // staging: chunk c -> (row = c>>2, slot = (c&3)^((c>>3)&3)); linear LDS dest,
    // pre-swizzled global source (rule #21)
    const int c0 = tid, c1 = tid + 512;
    const int r0 = c0 >> 2, z0 = ((c0 & 3) ^ ((c0 >> 3) & 3)) * 8;
    const int r1 = c1 >> 2, z1 = ((c1 & 3) ^ ((c1 >> 3) & 3)) * 8;

// stage k-half KH (global k offset KH*32) of matrix MAT into region REG
#define STAGE(REG, MAT, BASE, ROW0, KH) do {                                       \
    __builtin_amdgcn_global_load_lds(                                              \
        (const GLOBAL_AS short*)((BASE) + (size_t)((ROW0) + r0) * KDIM +           \
                                 (KH) * 32 + z0),                                  \
        (LDS_AS short*)&lds[REG][MAT][c0 * 8], 16, 0, 0);                          \
    __builtin_amdgcn_global_load_lds(                                              \
        (const GLOBAL_AS short*)((BASE) + (size_t)((ROW0) + r1) * KDIM +           \
                                 (KH) * 32 + z1),                                  \
        (LDS_AS short*)&lds[REG][MAT][c1 * 8], 16, 0, 0);                          \
} while (0)

#define LDA(REG, R) (*reinterpret_cast<const bf16x8*>(                             \
        &lds[REG][0][((R) * 4 + (ks ^ (((R) >> 1) & 3))) * 8]))
#define LDB(REG, R) (*reinterpret_cast<const bf16x8*>(                             \
        &lds[REG][1][((R) * 4 + (ks ^ (((R) >> 1) & 3))) * 8]))

    f32x4 acc[8][4];
    #pragma unroll
    for (int i = 0; i < 8; ++i)
        #pragma unroll
        for (int j = 0; j < 4; ++j)
            acc[i][j] = (f32x4){0.f, 0.f, 0.f, 0.f};

    bf16x8 af[8], bf[4];

// Phase: consume region RG, stage k-half HS into region (RG+3)&3.
#define PHASE(RG, HS) do {                                                         \
    _Pragma("unroll")                                                              \
    for (int mi = 0; mi < 8; ++mi)                                                 \
        af[mi] = LDA(RG, wr * 128 + mi * 16 + frow);                               \
    _Pragma("unroll")                                                              \
    for (int ni = 0; ni < 4; ++ni)                                                 \
        bf[ni] = LDB(RG, wc * 64 + ni * 16 + frow);                                \
    STAGE((RG + 3) & 3, 0, A,  m0, HS);                                            \
    STAGE((RG + 3) & 3, 1, Bm, n0, HS);                                            \
    __builtin_amdgcn_s_barrier();                                                  \
    asm volatile("s_waitcnt lgkmcnt(0)" ::: "memory");                             \
    __builtin_amdgcn_s_setprio(1);                                                 \
    _Pragma("unroll")                                                              \
    for (int mi = 0; mi < 8; ++mi)                                                 \
        _Pragma("unroll")                                                          \
        for (int ni = 0; ni < 4; ++ni)                                             \
            acc[mi][ni] = __builtin_amdgcn_mfma_f32_16x16x32_bf16(                 \
                              af[mi], bf[ni], acc[mi][ni], 0, 0, 0);               \
    __builtin_amdgcn_s_setprio(0);                                                 \
    asm volatile("s_waitcnt vmcnt(8)" ::: "memory");                               \
    __builtin_amdgcn_s_barrier();                                                  \
} while (0)

    // prologue: stage k-halves 0,1,2 into regions 0,1,2 (12 loads);
    // vmcnt(8) retires k-half 0's 4 loads in every wave; barrier.
    STAGE(0, 0, A, m0, 0);  STAGE(0, 1, Bm, n0, 0);
    STAGE(1, 0, A, m0, 1);  STAGE(1, 1, Bm, n0, 1);
    STAGE(2, 0, A, m0, 2);  STAGE(2, 1, Bm, n0, 2);
    asm volatile("s_waitcnt vmcnt(8)" ::: "memory");
    __builtin_amdgcn_s_barrier();

    #pragma unroll 1
    for (int it = 0; it < NKH / 4; ++it) {
        const int h = it * 4;
        const int s0 = (h + 3 < NKH) ? h + 3 : NKH - 1;
        const int s1 = (h + 4 < NKH) ? h + 4 : NKH - 1;
        const int s2 = (h + 5 < NKH) ? h + 5 : NKH - 1;
        const int s3 = (h + 6 < NKH) ? h + 6 : NKH - 1;
        PHASE(0, s0);
        PHASE(1, s1);
        PHASE(2, s2);
        PHASE(3, s3);
    }

    asm volatile("s_waitcnt vmcnt(0)" ::: "memory");   // drain tail prefetches

    // epilogue: C/D layout col = lane&15, row = (lane>>4)*4 + r
    const int crow = (lane >> 4) * 4;
    const int ccol = lane & 15;
    float bv4[4];
    #pragma unroll
    for (int ni = 0; ni < 4; ++ni)
        bv4[ni] = bias[n0 + wc * 64 + ni * 16 + ccol];
    #pragma unroll
    for (int mi = 0; mi < 8; ++mi) {
        #pragma unroll
        for (int r = 0; r < 4; ++r) {
            const size_t rowg = (size_t)(m0 + wr * 128 + mi * 16 + crow + r) * N;
            #pragma unroll
            for (int ni = 0; ni < 4; ++ni) {
                const int col = n0 + wc * 64 + ni * 16 + ccol;
                float v = acc[mi][ni][r] + bv4[ni];
                if constexpr (std::is_same<OutT, float>::value) {
                    C[rowg + col] = v;
                } else {
                    C[rowg + col] = f2b(v);
                }
            }
        }
    }
#undef PHASE
#undef LDA
#undef LDB
#undef STAGE
}

// ---------------- per-token head-mixing attention ----------------------
__global__ __launch_bounds__(256) void k_attn(
    const short* __restrict__ QKV, short* __restrict__ O)
{
    __shared__ short Ks[16][1032];
    __shared__ short Vs[16][1032];

    const int tid = threadIdx.x;
    const int tok0 = blockIdx.x * 16;

    for (int i = tid; i < 2048; i += 256) {
        int t = i >> 7;
        int j = i & 127;
        const size_t base = (size_t)(tok0 + t) * QKV_STRIDE;
        *reinterpret_cast<short8_t*>(&Ks[t][j * 8]) =
            *reinterpret_cast<const short8_t*>(&QKV[base + 1024 + j * 8]);
        *reinterpret_cast<short8_t*>(&Vs[t][j * 8]) =
            *reinterpret_cast<const short8_t*>(&QKV[base + 2048 + j * 8]);
    }
    __syncthreads();

    const int tl = tid >> 4;
    const int h  = tid & 15;

    float qf[64];
    const short* qp = QKV + (size_t)(tok0 + tl) * QKV_STRIDE + h * HD;
    #pragma unroll
    for (int i = 0; i < 8; ++i) {
        short8_t v = *reinterpret_cast<const short8_t*>(&qp[i * 8]);
        #pragma unroll
        for (int j = 0; j < 8; ++j) qf[i * 8 + j] = b2f(v[j]);
    }

    float s[16];
    #pragma unroll
    for (int g = 0; g < 16; ++g) {
        float a = 0.f;
        #pragma unroll
        for (int i = 0; i < 8; ++i) {
            short8_t kv = *reinterpret_cast<const short8_t*>(&Ks[tl][g * HD + i * 8]);
            #pragma unroll
            for (int j = 0; j < 8; ++j) a += qf[i * 8 + j] * b2f(kv[j]);
        }
        s[g] = a * 0.125f;
    }
    float mx = s[0];
    #pragma unroll
    for (int g = 1; g < 16; ++g) mx = fmaxf(mx, s[g]);
    float l = 0.f;
    #pragma unroll
    for (int g = 0; g < 16; ++g) { s[g] = __expf(s[g] - mx); l += s[g]; }
    const float inv = 1.f / l;
    #pragma unroll
    for (int g = 0; g < 16; ++g) s[g] *= inv;

    short* op = O + (size_t)(tok0 + tl) * E_DIM + h * HD;
    #pragma unroll
    for (int c = 0; c < 4; ++c) {
        float a[16];
        #pragma unroll
        for (int j = 0; j < 16; ++j) a[j] = 0.f;
        #pragma unroll
        for (int g = 0; g < 16; ++g) {
            short8_t v0 = *reinterpret_cast<const short8_t*>(&Vs[tl][g * HD + c * 16]);
            short8_t v1 = *reinterpret_cast<const short8_t*>(&Vs[tl][g * HD + c * 16 + 8]);
            #pragma unroll
            for (int j = 0; j < 8; ++j) {
                a[j]     += s[g] * b2f(v0[j]);
                a[8 + j] += s[g] * b2f(v1[j]);
            }
        }
        short8_t o0, o1;
        #pragma unroll
        for (int j = 0; j < 8; ++j) { o0[j] = f2b(a[j]); o1[j] = f2b(a[8 + j]); }
        *reinterpret_cast<short8_t*>(&op[c * 16])     = o0;
        *reinterpret_cast<short8_t*>(&op[c * 16 + 8]) = o1;
    }
}

extern "C" void kernel_launch(void* const* d_in, const int* in_sizes, int n_in,
                              void* d_out, int out_size, void* d_ws, size_t ws_size,
                              hipStream_t stream) {
    const float* x  = (const float*)d_in[0];
    const float* Wq = (const float*)d_in[1];
    const float* bq = (const float*)d_in[2];
    const float* Wk = (const float*)d_in[3];
    const float* bk = (const float*)d_in[4];
    const float* Wv = (const float*)d_in[5];
    const float* bv = (const float*)d_in[6];
    const float* Wo = (const float*)d_in[7];
    const float* bo = (const float*)d_in[8];
    float* out = (float*)d_out;

    const int T = in_sizes[0] / E_DIM;      // 32768 tokens
    char* ws = (char*)d_ws;
    const size_t SZ_X    = (size_t)T * E_DIM * 2;
    const size_t SZ_WQKV = (size_t)3 * E_DIM * E_DIM * 2;
    const size_t SZ_W    = (size_t)E_DIM * E_DIM * 2;
    const size_t SZ_B    = 3072 * sizeof(float) + 4096;

    short* xb    = (short*)(ws);
    short* Wqkvb = (short*)(ws + SZ_X);
    short* Wob   = (short*)(ws + SZ_X + SZ_WQKV);
    float* bqkv  = (float*)(ws + SZ_X + SZ_WQKV + SZ_W);
    short* QKVb  = (short*)(ws + SZ_X + SZ_WQKV + SZ_W + SZ_B);
    short* Ab    = xb;   // reuse x-bf16 buffer for attention output

    const int n4x = T * E_DIM / 4;
    const int n4w = E_DIM * E_DIM / 4;
    k_convert<<<dim3((n4x + 255) / 256), dim3(256), 0, stream>>>(x,  xb, n4x);
    k_convert<<<dim3((n4w + 255) / 256), dim3(256), 0, stream>>>(Wq, Wqkvb,                     n4w);
    k_convert<<<dim3((n4w + 255) / 256), dim3(256), 0, stream>>>(Wk, Wqkvb + E_DIM * E_DIM,     n4w);
    k_convert<<<dim3((n4w + 255) / 256), dim3(256), 0, stream>>>(Wv, Wqkvb + 2 * E_DIM * E_DIM, n4w);
    k_convert<<<dim3((n4w + 255) / 256), dim3(256), 0, stream>>>(Wo, Wob, n4w);
    k_bcat<<<dim3(12), dim3(256), 0, stream>>>(bq, bk, bv, bqkv);

    // fused QKV GEMM: [T][3072]
    k_gemm256<short><<<dim3((T / 256) * (QKV_STRIDE / 256)), dim3(512), 0, stream>>>(
        xb, Wqkvb, bqkv, QKVb, QKV_STRIDE / 256, QKV_STRIDE);

    k_attn<<<dim3(T / 16), dim3(256), 0, stream>>>(QKVb, Ab);

    // output GEMM: [T][1024] fp32
    k_gemm256<float><<<dim3((T / 256) * (E_DIM / 256)), dim3(512), 0, stream>>>(
        Ab, Wob, bo, out, E_DIM / 256, E_DIM);
}

// Round 6
// 426.130 us; speedup vs baseline: 1.0131x; 1.0131x over previous
//
#include <hip/hip_runtime.h>
#include <hip/hip_bf16.h>
#include <cstdint>
#include <type_traits>

#define GLOBAL_AS __attribute__((address_space(1)))
#define LDS_AS    __attribute__((address_space(3)))

typedef short bf16x8 __attribute__((ext_vector_type(8)));
typedef short short8_t __attribute__((ext_vector_type(8)));
typedef float f32x4  __attribute__((ext_vector_type(4)));

static constexpr int E_DIM = 1024;   // hidden
static constexpr int HD = 64;
static constexpr int QKV_STRIDE = 3072;
static constexpr int KDIM = 1024;        // K for both GEMMs
static constexpr int NKH  = KDIM / 32;   // 32 k-halves (phases)

__device__ __forceinline__ float b2f(short s) {
    union { unsigned u; float f; } x;
    x.u = ((unsigned)(unsigned short)s) << 16;
    return x.f;
}
__device__ __forceinline__ short f2b(float f) {
    union { float f; unsigned u; } x; x.f = f;
    unsigned r = x.u + 0x7FFF + ((x.u >> 16) & 1);
    return (short)(r >> 16);
}

// ---------------- fp32 -> bf16 convert ----------------
__global__ __launch_bounds__(256) void k_convert(const float* __restrict__ in,
                                                 short* __restrict__ out, int n4) {
    int i = blockIdx.x * 256 + threadIdx.x;
    if (i >= n4) return;
    float4 v = reinterpret_cast<const float4*>(in)[i];
    short4 o;
    o.x = f2b(v.x); o.y = f2b(v.y); o.z = f2b(v.z); o.w = f2b(v.w);
    reinterpret_cast<short4*>(out)[i] = o;
}

// ---------------- bias concat [bq | bk | bv] ----------
__global__ __launch_bounds__(256) void k_bcat(const float* __restrict__ bq,
                                              const float* __restrict__ bk,
                                              const float* __restrict__ bv,
                                              float* __restrict__ o) {
    int i = blockIdx.x * 256 + threadIdx.x;
    float v = (i < 1024) ? bq[i] : (i < 2048 ? bk[i - 1024] : bv[i - 2048]);
    o[i] = v;
}

// ==== 256x256 bf16 GEMM, ring-4 + REGISTER double-buffered fragments ====
// C[M][N] = A[M][K] * B[N][K]^T + bias. K = KDIM = 1024.
// 512 threads = 8 waves (2M x 4N), per-wave 128x64 output.
// Per phase h: stage khalf h+3 -> region (h+3)%4; issue 12 ds_read of region
// (h+1)%4 into ALTERNATE frag set; sched_barrier; 32 MFMA on current set
// (reads arrived during previous phase's MFMA); vmcnt(4); barrier.
// FIFO: phase-end vmcnt(4) retires stage S_{h+2} = region read at phase h+1,
// always before a barrier -> cross-wave safe. Read-before-overwrite has >=2
// barriers of slack (region r read at phase r-1(mod4 cycle), restaged r+1).
template <typename OutT>
__global__ __launch_bounds__(512, 2) void k_gemm256(
    const short* __restrict__ A,    // [M][KDIM]
    const short* __restrict__ Bm,   // [N][KDIM]
    const float* __restrict__ bias, // [N]
    OutT* __restrict__ C,           // [M][N]
    int NT_N, int N)
{
    __shared__ short lds[4][2][8192];   // [region][A=0/B=1][16 KiB]

    const int tid  = threadIdx.x;
    const int lane = tid & 63;
    const int wv   = tid >> 6;      // 0..7
    const int wr   = wv >> 2;       // 0..1  (M half)
    const int wc   = wv & 3;        // 0..3  (N quarter)
    const int frow = lane & 15;
    const int ks   = lane >> 4;     // k-slot 0..3 within k-half

    // bijective XCD swizzle (grid % 8 == 0), n-fastest so neighbors share A-panel
    const int nwg  = gridDim.x;
    const int nper = nwg >> 3;
    const int bid  = blockIdx.x;
    const int swz  = (bid & 7) * nper + (bid >> 3);
    const int m0   = (swz / NT_N) * 256;
    const int n0   = (swz % NT_N) * 256;

    // staging: chunk c -> (row = c>>2, slot = (c&3)^((c>>3)&3)); linear LDS dest,
    // pre-swizzled global source (rule #21)
    const int c0 = tid, c1 = tid + 512;
    const int r0 = c0 >> 2, z0 = ((c0 & 3) ^ ((c0 >> 3) & 3)) * 8;
    const int r1 = c1 >> 2, z1 = ((c1 & 3) ^ ((c1 >> 3) & 3)) * 8;

#define STAGE(REG, MAT, BASE, ROW0, KH) do {                                       \
    __builtin_amdgcn_global_load_lds(                                              \
        (const GLOBAL_AS short*)((BASE) + (size_t)((ROW0) + r0) * KDIM +           \
                                 (KH) * 32 + z0),                                  \
        (LDS_AS short*)&lds[REG][MAT][c0 * 8], 16, 0, 0);                          \
    __builtin_amdgcn_global_load_lds(                                              \
        (const GLOBAL_AS short*)((BASE) + (size_t)((ROW0) + r1) * KDIM +           \
                                 (KH) * 32 + z1),                                  \
        (LDS_AS short*)&lds[REG][MAT][c1 * 8], 16, 0, 0);                          \
} while (0)

#define LDA(REG, R) (*reinterpret_cast<const bf16x8*>(                             \
        &lds[REG][0][((R) * 4 + (ks ^ (((R) >> 1) & 3))) * 8]))
#define LDB(REG, R) (*reinterpret_cast<const bf16x8*>(                             \
        &lds[REG][1][((R) * 4 + (ks ^ (((R) >> 1) & 3))) * 8]))

    f32x4 acc[8][4];
    #pragma unroll
    for (int i = 0; i < 8; ++i)
        #pragma unroll
        for (int j = 0; j < 4; ++j)
            acc[i][j] = (f32x4){0.f, 0.f, 0.f, 0.f};

    bf16x8 afA[8], bfA[4], afB[8], bfB[4];

#define READF(AF, BF, RG) do {                                                     \
    _Pragma("unroll")                                                              \
    for (int mi = 0; mi < 8; ++mi)                                                 \
        AF[mi] = LDA(RG, wr * 128 + mi * 16 + frow);                               \
    _Pragma("unroll")                                                              \
    for (int ni = 0; ni < 4; ++ni)                                                 \
        BF[ni] = LDB(RG, wc * 64 + ni * 16 + frow);                                \
} while (0)

// Phase: stage khalf HS into RSTG, prefetch-read region RNEXT into (NAF,NBF),
// MFMA on (CAF,CBF), counted vmcnt, single barrier.
#define PHASE(CAF, CBF, NAF, NBF, RNEXT, RSTG, HS) do {                            \
    STAGE(RSTG, 0, A,  m0, HS);                                                    \
    STAGE(RSTG, 1, Bm, n0, HS);                                                    \
    READF(NAF, NBF, RNEXT);                                                        \
    __builtin_amdgcn_sched_barrier(0);                                             \
    __builtin_amdgcn_s_setprio(1);                                                 \
    _Pragma("unroll")                                                              \
    for (int mi = 0; mi < 8; ++mi)                                                 \
        _Pragma("unroll")                                                          \
        for (int ni = 0; ni < 4; ++ni)                                             \
            acc[mi][ni] = __builtin_amdgcn_mfma_f32_16x16x32_bf16(                 \
                              CAF[mi], CBF[ni], acc[mi][ni], 0, 0, 0);             \
    __builtin_amdgcn_s_setprio(0);                                                 \
    asm volatile("s_waitcnt vmcnt(4)" ::: "memory");                               \
    __builtin_amdgcn_s_barrier();                                                  \
} while (0)

    // prologue: stage khalves 0,1,2 into regions 0,1,2 (12 loads);
    // vmcnt(4) retires S0+S1 in every wave; barrier; read cur <- region 0.
    STAGE(0, 0, A, m0, 0);  STAGE(0, 1, Bm, n0, 0);
    STAGE(1, 0, A, m0, 1);  STAGE(1, 1, Bm, n0, 1);
    STAGE(2, 0, A, m0, 2);  STAGE(2, 1, Bm, n0, 2);
    asm volatile("s_waitcnt vmcnt(4)" ::: "memory");
    __builtin_amdgcn_s_barrier();
    READF(afA, bfA, 0);

    #pragma unroll 1
    for (int it = 0; it < NKH / 4; ++it) {
        const int h0 = it * 4;
        const int s0 = (h0 + 3 < NKH) ? h0 + 3 : NKH - 1;
        const int s1 = (h0 + 4 < NKH) ? h0 + 4 : NKH - 1;
        const int s2 = (h0 + 5 < NKH) ? h0 + 5 : NKH - 1;
        const int s3 = (h0 + 6 < NKH) ? h0 + 6 : NKH - 1;
        PHASE(afA, bfA, afB, bfB, 1, 3, s0);   // phase h0+0: cur=R0 data
        PHASE(afB, bfB, afA, bfA, 2, 0, s1);   // phase h0+1: cur=R1 data
        PHASE(afA, bfA, afB, bfB, 3, 1, s2);   // phase h0+2: cur=R2 data
        PHASE(afB, bfB, afA, bfA, 0, 2, s3);   // phase h0+3: cur=R3 data
    }

    asm volatile("s_waitcnt vmcnt(0)" ::: "memory");   // drain tail prefetches

    // epilogue: C/D layout col = lane&15, row = (lane>>4)*4 + r
    const int crow = (lane >> 4) * 4;
    const int ccol = lane & 15;
    float bv4[4];
    #pragma unroll
    for (int ni = 0; ni < 4; ++ni)
        bv4[ni] = bias[n0 + wc * 64 + ni * 16 + ccol];
    #pragma unroll
    for (int mi = 0; mi < 8; ++mi) {
        #pragma unroll
        for (int r = 0; r < 4; ++r) {
            const size_t rowg = (size_t)(m0 + wr * 128 + mi * 16 + crow + r) * N;
            #pragma unroll
            for (int ni = 0; ni < 4; ++ni) {
                const int col = n0 + wc * 64 + ni * 16 + ccol;
                float v = acc[mi][ni][r] + bv4[ni];
                if constexpr (std::is_same<OutT, float>::value) {
                    C[rowg + col] = v;
                } else {
                    C[rowg + col] = f2b(v);
                }
            }
        }
    }
#undef PHASE
#undef READF
#undef LDA
#undef LDB
#undef STAGE
}

// ---------------- per-token head-mixing attention ----------------------
__global__ __launch_bounds__(256) void k_attn(
    const short* __restrict__ QKV, short* __restrict__ O)
{
    __shared__ short Ks[16][1032];
    __shared__ short Vs[16][1032];

    const int tid = threadIdx.x;
    const int tok0 = blockIdx.x * 16;

    for (int i = tid; i < 2048; i += 256) {
        int t = i >> 7;
        int j = i & 127;
        const size_t base = (size_t)(tok0 + t) * QKV_STRIDE;
        *reinterpret_cast<short8_t*>(&Ks[t][j * 8]) =
            *reinterpret_cast<const short8_t*>(&QKV[base + 1024 + j * 8]);
        *reinterpret_cast<short8_t*>(&Vs[t][j * 8]) =
            *reinterpret_cast<const short8_t*>(&QKV[base + 2048 + j * 8]);
    }
    __syncthreads();

    const int tl = tid >> 4;
    const int h  = tid & 15;

    float qf[64];
    const short* qp = QKV + (size_t)(tok0 + tl) * QKV_STRIDE + h * HD;
    #pragma unroll
    for (int i = 0; i < 8; ++i) {
        short8_t v = *reinterpret_cast<const short8_t*>(&qp[i * 8]);
        #pragma unroll
        for (int j = 0; j < 8; ++j) qf[i * 8 + j] = b2f(v[j]);
    }

    float s[16];
    #pragma unroll
    for (int g = 0; g < 16; ++g) {
        float a = 0.f;
        #pragma unroll
        for (int i = 0; i < 8; ++i) {
            short8_t kv = *reinterpret_cast<const short8_t*>(&Ks[tl][g * HD + i * 8]);
            #pragma unroll
            for (int j = 0; j < 8; ++j) a += qf[i * 8 + j] * b2f(kv[j]);
        }
        s[g] = a * 0.125f;
    }
    float mx = s[0];
    #pragma unroll
    for (int g = 1; g < 16; ++g) mx = fmaxf(mx, s[g]);
    float l = 0.f;
    #pragma unroll
    for (int g = 0; g < 16; ++g) { s[g] = __expf(s[g] - mx); l += s[g]; }
    const float inv = 1.f / l;
    #pragma unroll
    for (int g = 0; g < 16; ++g) s[g] *= inv;

    short* op = O + (size_t)(tok0 + tl) * E_DIM + h * HD;
    #pragma unroll
    for (int c = 0; c < 4; ++c) {
        float a[16];
        #pragma unroll
        for (int j = 0; j < 16; ++j) a[j] = 0.f;
        #pragma unroll
        for (int g = 0; g < 16; ++g) {
            short8_t v0 = *reinterpret_cast<const short8_t*>(&Vs[tl][g * HD + c * 16]);
            short8_t v1 = *reinterpret_cast<const short8_t*>(&Vs[tl][g * HD + c * 16 + 8]);
            #pragma unroll
            for (int j = 0; j < 8; ++j) {
                a[j]     += s[g] * b2f(v0[j]);
                a[8 + j] += s[g] * b2f(v1[j]);
            }
        }
        short8_t o0, o1;
        #pragma unroll
        for (int j = 0; j < 8; ++j) { o0[j] = f2b(a[j]); o1[j] = f2b(a[8 + j]); }
        *reinterpret_cast<short8_t*>(&op[c * 16])     = o0;
        *reinterpret_cast<short8_t*>(&op[c * 16 + 8]) = o1;
    }
}

extern "C" void kernel_launch(void* const* d_in, const int* in_sizes, int n_in,
                              void* d_out, int out_size, void* d_ws, size_t ws_size,
                              hipStream_t stream) {
    const float* x  = (const float*)d_in[0];
    const float* Wq = (const float*)d_in[1];
    const float* bq = (const float*)d_in[2];
    const float* Wk = (const float*)d_in[3];
    const float* bk = (const float*)d_in[4];
    const float* Wv = (const float*)d_in[5];
    const float* bv = (const float*)d_in[6];
    const float* Wo = (const float*)d_in[7];
    const float* bo = (const float*)d_in[8];
    float* out = (float*)d_out;

    const int T = in_sizes[0] / E_DIM;      // 32768 tokens
    char* ws = (char*)d_ws;
    const size_t SZ_X    = (size_t)T * E_DIM * 2;
    const size_t SZ_WQKV = (size_t)3 * E_DIM * E_DIM * 2;
    const size_t SZ_W    = (size_t)E_DIM * E_DIM * 2;
    const size_t SZ_B    = 3072 * sizeof(float) + 4096;

    short* xb    = (short*)(ws);
    short* Wqkvb = (short*)(ws + SZ_X);
    short* Wob   = (short*)(ws + SZ_X + SZ_WQKV);
    float* bqkv  = (float*)(ws + SZ_X + SZ_WQKV + SZ_W);
    short* QKVb  = (short*)(ws + SZ_X + SZ_WQKV + SZ_W + SZ_B);
    short* Ab    = xb;   // reuse x-bf16 buffer for attention output

    const int n4x = T * E_DIM / 4;
    const int n4w = E_DIM * E_DIM / 4;
    k_convert<<<dim3((n4x + 255) / 256), dim3(256), 0, stream>>>(x,  xb, n4x);
    k_convert<<<dim3((n4w + 255) / 256), dim3(256), 0, stream>>>(Wq, Wqkvb,                     n4w);
    k_convert<<<dim3((n4w + 255) / 256), dim3(256), 0, stream>>>(Wk, Wqkvb + E_DIM * E_DIM,     n4w);
    k_convert<<<dim3((n4w + 255) / 256), dim3(256), 0, stream>>>(Wv, Wqkvb + 2 * E_DIM * E_DIM, n4w);
    k_convert<<<dim3((n4w + 255) / 256), dim3(256), 0, stream>>>(Wo, Wob, n4w);
    k_bcat<<<dim3(12), dim3(256), 0, stream>>>(bq, bk, bv, bqkv);

    // fused QKV GEMM: [T][3072]
    k_gemm256<short><<<dim3((T / 256) * (QKV_STRIDE / 256)), dim3(512), 0, stream>>>(
        xb, Wqkvb, bqkv, QKVb, QKV_STRIDE / 256, QKV_STRIDE);

    k_attn<<<dim3(T / 16), dim3(256), 0, stream>>>(QKVb, Ab);

    // output GEMM: [T][1024] fp32
    k_gemm256<float><<<dim3((T / 256) * (E_DIM / 256)), dim3(512), 0, stream>>>(
        Ab, Wob, bo, out, E_DIM / 256, E_DIM);
}